// Round 6
// baseline (186.450 us; speedup 1.0000x reference)
//
#include <hip/hip_runtime.h>
#include <cstdint>
#include <cstddef>

#define NH     12
#define DH     64
#define CIN    768
#define NPIX   196
#define NB     64
#define ROWS   (NB * NPIX)      // 12544
#define QKV_OC 2304
#define NKT    12               // 768/64

typedef __attribute__((ext_vector_type(8))) _Float16 f16x8;
typedef __attribute__((ext_vector_type(4))) _Float16 f16x4;
typedef __attribute__((ext_vector_type(4))) float    f32x4;

#define MFMA16 __builtin_amdgcn_mfma_f32_16x16x32_f16

// ---------------------------------------------------------------- weights → fp16
__global__ __launch_bounds__(256) void k_convert_w(const float* __restrict__ wq,
                                                   const float* __restrict__ wp,
                                                   _Float16* __restrict__ out) {
    int i = blockIdx.x * 256 + threadIdx.x;
    const int NQ = QKV_OC * CIN / 4;
    const int NT = NQ + (CIN * CIN) / 4;
    if (i >= NT) return;
    float4 v = (i < NQ) ? ((const float4*)wq)[i] : ((const float4*)wp)[i - NQ];
    f16x4 o = { (_Float16)v.x, (_Float16)v.y, (_Float16)v.z, (_Float16)v.w };
    ((f16x4*)out)[i] = o;
}

// ------------------------------------------------- x [b][c][n] f32 → Xt [b*196+n][c] f16
__global__ __launch_bounds__(256) void k_transpose_x(const float* __restrict__ x,
                                                     _Float16* __restrict__ Xt) {
    __shared__ __align__(16) _Float16 lds[NPIX][72];
    int t  = threadIdx.x;
    int b  = blockIdx.y, c0 = blockIdx.x * 64;
    const float* xp = x + ((size_t)b * CIN + c0) * NPIX;
    for (int idx = t; idx < 64 * 49; idx += 256) {
        int c = idx / 49, k = idx - c * 49;
        float4 v = *(const float4*)(xp + (size_t)c * NPIX + k * 4);
        int n = k * 4;
        lds[n][c]     = (_Float16)v.x;
        lds[n + 1][c] = (_Float16)v.y;
        lds[n + 2][c] = (_Float16)v.z;
        lds[n + 3][c] = (_Float16)v.w;
    }
    __syncthreads();
    int cs = t & 7, nn = t >> 3;
    for (int n = nn; n < NPIX; n += 32) {
        _Float16* dst = Xt + ((size_t)(b * NPIX + n)) * CIN + c0 + cs * 8;
        *(ulonglong2*)dst = *(const ulonglong2*)&lds[n][cs * 8];
    }
}

// ---------------------------------------------------------------- helpers
__device__ inline void gload16(const _Float16* g, _Float16* l) {
    __builtin_amdgcn_global_load_lds((const __attribute__((address_space(1))) void*)g,
                                     (__attribute__((address_space(3))) void*)l,
                                     16, 0, 0);
}

// ---------------------------------------------------------------- 256x256 2-barrier GEMM
// B-DIRECT variant of the R0 proven skeleton: A stays LDS-staged (identical sync
// choreography); B fragments load global->register (the mfma 16x16x32 B-layout —
// lane row=r16, k=q4*8+j — is a natural coalesced 16B global read; B panels are
// L2/L3-resident). Deletes Bs/stageB + 8 B ds_reads per wave per tile.
// vmcnt: only A-stage loads remain un-consumed at the tile-end wait (B loads are
// retired by compiler-inserted waits before their MFMAs; the VMEM queue retires
// in order, m135) -> vmcnt(4) guarantees tile t+1's A staged. Prologue likewise.
// C[r][o] = sum_c A[r][c]*B[o][c]; A:[12544][768], B:[NTN*256][768]
// PROJ=false: C f16 [row][2304];  PROJ=true: Cf f32 out[b][col][n]
template<int NTN, bool PROJ>
__global__ __launch_bounds__(512, 2) void k_gemm2(const _Float16* __restrict__ A,
                                                  const _Float16* __restrict__ Bm,
                                                  _Float16* __restrict__ Cb,
                                                  float* __restrict__ Cf) {
    __shared__ __align__(16) _Float16 As[2][256 * 64];   // 64 KiB total
    int tid = threadIdx.x;
    int w = tid >> 6, lane = tid & 63;

    // T1: bijective XCD swizzle
    int nwg = gridDim.x;
    int orig = blockIdx.x;
    int q = nwg >> 3, r = nwg & 7;
    int xcd = orig & 7, within = orig >> 3;
    int wg = (xcd < r ? xcd * (q + 1) : r * (q + 1) + (xcd - r) * q) + within;
    int bm = wg / NTN, bn = wg - bm * NTN;
    int m0 = bm * 256, n0 = bn * 256;

    int wr = w >> 2, wc = w & 3;          // 2 x 4 wave grid
    int r16 = lane & 15, q4 = lane >> 4;

    // A staging (T2: inverse-swizzled global source; linear LDS dest)
    int sr8  = (w << 3) + (lane >> 3);                    // 0..63
    int swz8 = ((lane & 7) ^ (lane >> 3)) << 3;
    const _Float16* Ag = A + (size_t)(m0 + sr8) * CIN + swz8;

    auto stageA = [&](int buf, int kt) {
        const _Float16* g = Ag + kt * 64;
        _Float16* l0 = As[buf] + (w << 9);
        gload16(g,             l0);
        gload16(g +  64 * CIN, l0 + 4096);
        gload16(g + 128 * CIN, l0 + 8192);
        gload16(g + 192 * CIN, l0 + 12288);
    };

    // B direct: per-lane fragment base. Fragment (jj = 16-row col subtile, h = k-slab):
    //   B[n0 + wc*64 + jj*16 + r16][t*64 + h*32 + q4*8 .. +7]  (16B aligned)
    const _Float16* Bg = Bm + (size_t)(n0 + (wc << 6) + r16) * CIN + (q4 << 3);

    int cS0 = ((q4)     ^ (r16 & 7)) << 3;
    int cS1 = ((q4 + 4) ^ (r16 & 7)) << 3;

    f32x4 acc[8][4];
#pragma unroll
    for (int i = 0; i < 8; i++)
#pragma unroll
        for (int j = 0; j < 4; j++) acc[i][j] = (f32x4){0.f, 0.f, 0.f, 0.f};

    // prologue: stage A tiles 0 and 1 (4 loads each); wait for tile 0
    stageA(0, 0); stageA(1, 1);
    asm volatile("s_waitcnt vmcnt(4)" ::: "memory");
    __builtin_amdgcn_sched_barrier(0);
    __builtin_amdgcn_s_barrier();

#pragma unroll 2
    for (int t = 0; t < NKT; ++t) {
        int bt = t & 1;
        const _Float16* Ab = As[bt] + ((wr << 7) + r16) * 64;
        bool pre = (t + 2 < NKT);

        // B fragments for this K-tile: 8 x 16B global loads (L2-hot), issued first
        // so their latency hides under the A ds_reads.
        f16x8 bf[4][2];
#pragma unroll
        for (int jj = 0; jj < 4; jj++)
#pragma unroll
            for (int h = 0; h < 2; h++)
                bf[jj][h] = *(const f16x8*)(Bg + (size_t)jj * 16 * CIN + t * 64 + h * 32);

        // A fragments: 16 x ds_read_b128
        f16x8 a0[4][2], a1[4][2];
#pragma unroll
        for (int i = 0; i < 4; i++) {
            a0[i][0] = *(const f16x8*)(Ab + (i << 10) + cS0);
            a0[i][1] = *(const f16x8*)(Ab + (i << 10) + cS1);
            a1[i][0] = *(const f16x8*)(Ab + 4096 + (i << 10) + cS0);
            a1[i][1] = *(const f16x8*)(Ab + 4096 + (i << 10) + cS1);
        }

        // MFMA burst 1: output cols 0-31 (jj=0,1)
        __builtin_amdgcn_s_setprio(1);
#pragma unroll
        for (int i = 0; i < 4; i++)
#pragma unroll
            for (int j = 0; j < 2; j++) {
                acc[i][j]     = MFMA16(a0[i][0], bf[j][0], acc[i][j],     0, 0, 0);
                acc[i][j]     = MFMA16(a0[i][1], bf[j][1], acc[i][j],     0, 0, 0);
                acc[4 + i][j] = MFMA16(a1[i][0], bf[j][0], acc[4 + i][j], 0, 0, 0);
                acc[4 + i][j] = MFMA16(a1[i][1], bf[j][1], acc[4 + i][j], 0, 0, 0);
            }
        __builtin_amdgcn_s_setprio(0);

        // all 16 A-reads complete for every wave at this barrier
        asm volatile("s_waitcnt lgkmcnt(0)" ::: "memory");
        __builtin_amdgcn_sched_barrier(0);
        __builtin_amdgcn_s_barrier();

        // stage A tile t+2 into the buffer we just finished reading
        if (pre) stageA(bt, t + 2);

        // MFMA burst 2: output cols 32-63 (jj=2,3)
        __builtin_amdgcn_s_setprio(1);
#pragma unroll
        for (int i = 0; i < 4; i++)
#pragma unroll
            for (int j = 0; j < 2; j++) {
                acc[i][2 + j]     = MFMA16(a0[i][0], bf[2 + j][0], acc[i][2 + j],     0, 0, 0);
                acc[i][2 + j]     = MFMA16(a0[i][1], bf[2 + j][1], acc[i][2 + j],     0, 0, 0);
                acc[4 + i][2 + j] = MFMA16(a1[i][0], bf[2 + j][0], acc[4 + i][2 + j], 0, 0, 0);
                acc[4 + i][2 + j] = MFMA16(a1[i][1], bf[2 + j][1], acc[4 + i][2 + j], 0, 0, 0);
            }
        __builtin_amdgcn_s_setprio(0);

        // A tile t+1 must be resident before next iteration's reads.
        // Outstanding VMEM here: only the 4 stageA(t+2) loads (B loads retired
        // before their MFMAs) -> vmcnt(4) ensures the older t+1 loads retired.
        if (pre) { asm volatile("s_waitcnt vmcnt(4)" ::: "memory"); }
        else     { asm volatile("s_waitcnt vmcnt(0)" ::: "memory"); }
        __builtin_amdgcn_sched_barrier(0);
        __builtin_amdgcn_s_barrier();
    }

    if (!PROJ) {
#pragma unroll
        for (int hh = 0; hh < 2; hh++)
#pragma unroll
            for (int i = 0; i < 4; i++)
#pragma unroll
                for (int rr = 0; rr < 4; rr++) {
                    int row = m0 + (wr << 7) + hh * 64 + i * 16 + q4 * 4 + rr;
                    _Float16* cp = Cb + (size_t)row * QKV_OC + n0 + (wc << 6) + r16;
#pragma unroll
                    for (int g = 0; g < 2; g++)
#pragma unroll
                        for (int j = 0; j < 2; j++)
                            cp[g * 32 + j * 16] = (_Float16)acc[hh * 4 + i][g * 2 + j][rr];
                }
    } else {
#pragma unroll
        for (int hh = 0; hh < 2; hh++)
#pragma unroll
            for (int i = 0; i < 4; i++) {
                int row = m0 + (wr << 7) + hh * 64 + i * 16 + q4 * 4;  // mult of 4
                int b = row / NPIX;
                int n = row - b * NPIX;                                 // 196%4==0: no straddle
#pragma unroll
                for (int g = 0; g < 2; g++)
#pragma unroll
                    for (int j = 0; j < 2; j++) {
                        int col = n0 + (wc << 6) + g * 32 + j * 16 + r16;
                        f32x4 a = acc[hh * 4 + i][g * 2 + j];
                        float4 o; o.x = a[0]; o.y = a[1]; o.z = a[2]; o.w = a[3];
                        *(float4*)(Cf + ((size_t)b * CIN + col) * NPIX + n) = o;
                    }
            }
    }
}

// ---------------------------------------------------------------- fused attention
// 512 threads = 8 waves per (b,h) block (R5 verified). K/V staged once; q-tiles
// split 13-over-8 waves -> max serial depth 2. LDS 109568 B, 8 waves/CU.
__global__ __launch_bounds__(512) void k_attn(const _Float16* __restrict__ qkv,
                                              _Float16* __restrict__ Ot) {
    __shared__ __align__(16) _Float16 Kl[208 * 64];
    __shared__ __align__(16) _Float16 Vt[64][216];
    __shared__ __align__(16) _Float16 Pl[8][16][216];
    int tid = threadIdx.x, wave = tid >> 6, lane = tid & 63;
    int bh = blockIdx.x;
    int b = bh / NH, h = bh - b * NH;
    const _Float16* base  = qkv + (size_t)b * NPIX * QKV_OC + h * DH;  // Q
    const _Float16* kb    = base + CIN;                                 // K
    const _Float16* vbase = base + 2 * CIN;                             // V

    {
        int c8 = lane & 7;
#pragma unroll
        for (int rr = 0; rr < 4; ++rr) {
            int grp = wave + rr * 8;
            if (grp < 26) {
                int row = grp * 8 + (lane >> 3);
                const _Float16* src = kb + (size_t)row * QKV_OC + ((c8 ^ (row & 7)) << 3);
                gload16(src, Kl + row * 64 + (c8 << 3));
            }
        }
    }
    for (int task = tid; task < 208 * 8; task += 512) {
        int m = task >> 3, dc = (task & 7) * 8;
        f16x8 v = *(const f16x8*)(vbase + (size_t)m * QKV_OC + dc);
#pragma unroll
        for (int j = 0; j < 8; j++) Vt[dc + j][m] = v[j];
    }
    __syncthreads();

    int r16 = lane & 15, q4 = lane >> 4, r7 = r16 & 7;
    int kc0 = ((q4)     ^ r7) << 3;
    int kc1 = ((q4 + 4) ^ r7) << 3;
    const float s2 = 0.125f;

    for (int nt = wave; nt < 13; nt += 8) {
        f16x8 aq0 = *(const f16x8*)(base + (size_t)(nt * 16 + r16) * QKV_OC + q4 * 8);
        f16x8 aq1 = *(const f16x8*)(base + (size_t)(nt * 16 + r16) * QKV_OC + 32 + q4 * 8);
        f32x4 L[13];
#pragma unroll
        for (int mt = 0; mt < 13; ++mt) {
            const _Float16* kr = Kl + (mt * 16 + r16) * 64;
            f16x8 bk0 = *(const f16x8*)(kr + kc0);
            f16x8 bk1 = *(const f16x8*)(kr + kc1);
            f32x4 s = {0.f, 0.f, 0.f, 0.f};
            s = MFMA16(aq0, bk0, s, 0, 0, 0);
            s = MFMA16(aq1, bk1, s, 0, 0, 0);
            L[mt] = s;
        }
        float mx[4] = {-1e30f, -1e30f, -1e30f, -1e30f};
#pragma unroll
        for (int mt = 0; mt < 13; ++mt)
#pragma unroll
            for (int r = 0; r < 4; ++r) {
                float lv = L[mt][r] * s2;
                if (mt == 12 && r16 >= 4) lv = -1e30f;   // mask m >= 196
                L[mt][r] = lv;
                mx[r] = fmaxf(mx[r], lv);
            }
#pragma unroll
        for (int r = 0; r < 4; ++r)
            for (int off = 1; off < 16; off <<= 1)
                mx[r] = fmaxf(mx[r], __shfl_xor(mx[r], off));
        float sm[4] = {0.f, 0.f, 0.f, 0.f};
#pragma unroll
        for (int mt = 0; mt < 13; ++mt)
#pragma unroll
            for (int r = 0; r < 4; ++r) {
                float p = exp2f((L[mt][r] - mx[r]) * 1.44269504f);
                sm[r] += p;
                Pl[wave][q4 * 4 + r][mt * 16 + r16] = (_Float16)p;
            }
#pragma unroll
        for (int r = 0; r < 4; ++r)
            for (int off = 1; off < 16; off <<= 1)
                sm[r] += __shfl_xor(sm[r], off);

        f32x4 oacc[4];
#pragma unroll
        for (int di = 0; di < 4; ++di) oacc[di] = (f32x4){0.f, 0.f, 0.f, 0.f};
#pragma unroll
        for (int mc = 0; mc < 6; ++mc) {
            f16x8 ap = *(const f16x8*)&Pl[wave][r16][mc * 32 + q4 * 8];
#pragma unroll
            for (int di = 0; di < 4; ++di) {
                f16x8 bv = *(const f16x8*)&Vt[di * 16 + r16][mc * 32 + q4 * 8];
                oacc[di] = MFMA16(ap, bv, oacc[di], 0, 0, 0);
            }
        }
        {
            _Float16 z = (_Float16)0.f;
            f16x8 zz = (f16x8){z, z, z, z, z, z, z, z};
            f16x8 ap = (q4 < 2) ? *(const f16x8*)&Pl[wave][r16][192 + q4 * 8] : zz;
#pragma unroll
            for (int di = 0; di < 4; ++di) {
                f16x8 bv = (q4 < 2) ? *(const f16x8*)&Vt[di * 16 + r16][192 + q4 * 8] : zz;
                oacc[di] = MFMA16(ap, bv, oacc[di], 0, 0, 0);
            }
        }
#pragma unroll
        for (int r = 0; r < 4; ++r) {
            int n = nt * 16 + q4 * 4 + r;
            if (n < NPIX) {
                float rinv = 1.0f / sm[r];
                _Float16* op = Ot + (size_t)(b * NPIX + n) * CIN + h * DH + r16;
#pragma unroll
                for (int di = 0; di < 4; ++di)
                    op[di * 16] = (_Float16)(oacc[di][r] * rinv);
            }
        }
    }
}

// ---------------------------------------------------------------- launch
extern "C" void kernel_launch(void* const* d_in, const int* in_sizes, int n_in,
                              void* d_out, int out_size, void* d_ws, size_t ws_size,
                              hipStream_t stream) {
    const float* x  = (const float*)d_in[0];
    const float* wq = (const float*)d_in[1];
    const float* wp = (const float*)d_in[2];
    float* out = (float*)d_out;
    char* ws = (char*)d_ws;

    _Float16* Xt  = (_Float16*)(ws);
    _Float16* W   = (_Float16*)(ws + 20447232);
    _Float16* qkv = (_Float16*)(ws + 25165824);
    _Float16* Ot  = (_Float16*)(ws + 86507520);
    _Float16* Wq = W;
    _Float16* Wp = W + (size_t)QKV_OC * CIN;

    hipLaunchKernelGGL(k_convert_w, dim3(2304), dim3(256), 0, stream, wq, wp, W);
    hipLaunchKernelGGL(k_transpose_x, dim3(12, 64), dim3(256), 0, stream, x, Xt);
    hipLaunchKernelGGL((k_gemm2<9, false>), dim3(49 * 9), dim3(512), 0, stream,
                       Xt, Wq, qkv, (float*)nullptr);
    hipLaunchKernelGGL(k_attn, dim3(768), dim3(512), 0, stream, qkv, Ot);
    hipLaunchKernelGGL((k_gemm2<3, true>), dim3(49 * 3), dim3(512), 0, stream,
                       Ot, Wp, (_Float16*)nullptr, out);
}

// Round 7
// 177.755 us; speedup vs baseline: 1.0489x; 1.0489x over previous
//
#include <hip/hip_runtime.h>
#include <cstdint>
#include <cstddef>

#define NH     12
#define DH     64
#define CIN    768
#define NPIX   196
#define NB     64
#define ROWS   (NB * NPIX)      // 12544
#define QKV_OC 2304
#define NKT2   24               // 768/32

typedef __attribute__((ext_vector_type(8))) _Float16 f16x8;
typedef __attribute__((ext_vector_type(4))) _Float16 f16x4;
typedef __attribute__((ext_vector_type(4))) float    f32x4;

#define MFMA16 __builtin_amdgcn_mfma_f32_16x16x32_f16

// ---------------------------------------------------------------- weights → fp16
__global__ __launch_bounds__(256) void k_convert_w(const float* __restrict__ wq,
                                                   const float* __restrict__ wp,
                                                   _Float16* __restrict__ out) {
    int i = blockIdx.x * 256 + threadIdx.x;
    const int NQ = QKV_OC * CIN / 4;
    const int NT = NQ + (CIN * CIN) / 4;
    if (i >= NT) return;
    float4 v = (i < NQ) ? ((const float4*)wq)[i] : ((const float4*)wp)[i - NQ];
    f16x4 o = { (_Float16)v.x, (_Float16)v.y, (_Float16)v.z, (_Float16)v.w };
    ((f16x4*)out)[i] = o;
}

// ------------------------------------------------- x [b][c][n] f32 → Xt [b*196+n][c] f16
__global__ __launch_bounds__(256) void k_transpose_x(const float* __restrict__ x,
                                                     _Float16* __restrict__ Xt) {
    __shared__ __align__(16) _Float16 lds[NPIX][72];
    int t  = threadIdx.x;
    int b  = blockIdx.y, c0 = blockIdx.x * 64;
    const float* xp = x + ((size_t)b * CIN + c0) * NPIX;
    for (int idx = t; idx < 64 * 49; idx += 256) {
        int c = idx / 49, k = idx - c * 49;
        float4 v = *(const float4*)(xp + (size_t)c * NPIX + k * 4);
        int n = k * 4;
        lds[n][c]     = (_Float16)v.x;
        lds[n + 1][c] = (_Float16)v.y;
        lds[n + 2][c] = (_Float16)v.z;
        lds[n + 3][c] = (_Float16)v.w;
    }
    __syncthreads();
    int cs = t & 7, nn = t >> 3;
    for (int n = nn; n < NPIX; n += 32) {
        _Float16* dst = Xt + ((size_t)(b * NPIX + n)) * CIN + c0 + cs * 8;
        *(ulonglong2*)dst = *(const ulonglong2*)&lds[n][cs * 8];
    }
}

// ---------------------------------------------------------------- helpers
__device__ inline void gload16(const _Float16* g, _Float16* l) {
    __builtin_amdgcn_global_load_lds((const __attribute__((address_space(1))) void*)g,
                                     (__attribute__((address_space(3))) void*)l,
                                     16, 0, 0);
}

// ---------------------------------------------------------------- 256x256 GEMM, BK=32
// A: LDS-staged (R2-proven swizzle + gload_lds, 8 waves x 2 gloads/tile).
// B: global->register, DOUBLE-BUFFERED one full K-tile ahead (fixes R6's
// synchronous-latency regression; B panels are L2-resident, latency hides
// under the previous tile's reads+MFMA).
// 512 thr = 8 waves (2x4), wave tile 128x64, acc[8][4] = 128 AGPR;
// VGPR ~90 + 128 AGPR = ~218 <= 256 -> 2 waves/SIMD (no R3-style spill).
// Sync skeleton = R2's proven 2-burst:
//   reads -> burst1 -> lgkm0+bar -> stageA(t+2) -> burst2 -> counted vmcnt + bar
// vmcnt invariant (in-order VMEM queue): at tile end outstanding =
//   bnxt(4, tile top) + stageA(t+2)(2, mid) ; vmcnt(2) drains A(t+1)+B(t+1),
//   leaves A(t+2). Last tiles drain fully.
template<int NTN, bool PROJ>
__global__ __launch_bounds__(512, 2) void k_gemm2(const _Float16* __restrict__ A,
                                                  const _Float16* __restrict__ Bm,
                                                  _Float16* __restrict__ Cb,
                                                  float* __restrict__ Cf) {
    __shared__ __align__(16) _Float16 As[2][256 * 32];   // 16 KiB per buf, 32 KiB total
    int tid = threadIdx.x;
    int w = tid >> 6, lane = tid & 63;

    // T1: bijective XCD swizzle
    int nwg = gridDim.x;
    int orig = blockIdx.x;
    int q = nwg >> 3, r = nwg & 7;
    int xcd = orig & 7, within = orig >> 3;
    int wg = (xcd < r ? xcd * (q + 1) : r * (q + 1) + (xcd - r) * q) + within;
    int bm = wg / NTN, bn = wg - bm * NTN;
    int m0 = bm * 256, n0 = bn * 256;

    int wr = w >> 2, wc = w & 3;          // 2 x 4 wave grid; wave tile 128x64
    int r16 = lane & 15, q4 = lane >> 4;

    // A staging (R2 swizzle math verbatim; 8 waves x 2 gloads = 256 rows x 32 k)
    int srow = (w << 5) + (lane >> 2);                    // w*32 + 0..15
    int gc8  = (((lane & 3) ^ ((lane >> 3) & 3)) << 3);   // inverse involution chunk
    const _Float16* Ag = A + (size_t)(m0 + srow) * CIN + gc8;

    auto stageA = [&](int buf, int kt) {
        _Float16* l0 = As[buf] + (w << 10);               // w*32 rows * 32 hw
        gload16(Ag + kt * 32,            l0);             // rows srow
        gload16(Ag + 16 * CIN + kt * 32, l0 + 512);       // rows srow+16
    };

    // B direct: fragment jj (16-col subtile), k-tile t:
    //   Bm[(n0 + wc*64 + jj*16 + r16)*CIN + t*32 + q4*8]  (16B aligned)
    const _Float16* Bg = Bm + (size_t)(n0 + (wc << 6) + r16) * CIN + (q4 << 3);

    // read-side swizzle (R2): chunk = q4 ^ ((row>>1)&3)
    int cS = ((q4 ^ ((r16 >> 1) & 3)) << 3);

    f32x4 acc[8][4];
#pragma unroll
    for (int i = 0; i < 8; i++)
#pragma unroll
        for (int j = 0; j < 4; j++) acc[i][j] = (f32x4){0.f, 0.f, 0.f, 0.f};

    f16x8 bA[4], bB[4];   // B double-buffer (static names, no runtime indexing)

    // prologue: B(0) -> bA, stage A tiles 0 and 1
#pragma unroll
    for (int jj = 0; jj < 4; jj++)
        bA[jj] = *(const f16x8*)(Bg + (size_t)jj * 16 * CIN);
    stageA(0, 0); stageA(1, 1);
    // drains B(0) + A(0), leaves A(1)x2
    asm volatile("s_waitcnt vmcnt(2)" ::: "memory");
    __builtin_amdgcn_sched_barrier(0);
    __builtin_amdgcn_s_barrier();

    // one K-tile; cur = B regs for tile t, nxt = loaded here for t+1
#define GTILE(T, BUF, CUR, NXT)                                                   \
    {                                                                             \
        if ((T) + 1 < NKT2) {                                                     \
            _Pragma("unroll")                                                     \
            for (int jj = 0; jj < 4; jj++)                                        \
                NXT[jj] = *(const f16x8*)(Bg + (size_t)jj * 16 * CIN + ((T) + 1) * 32); \
        }                                                                         \
        const _Float16* Ab = As[BUF] + ((wr << 7) + r16) * 32 + cS;               \
        f16x8 a[8];                                                               \
        _Pragma("unroll")                                                         \
        for (int i = 0; i < 8; i++) a[i] = *(const f16x8*)(Ab + (i << 9));        \
        __builtin_amdgcn_s_setprio(1);                                            \
        _Pragma("unroll")                                                         \
        for (int i = 0; i < 8; i++) {                                             \
            acc[i][0] = MFMA16(a[i], CUR[0], acc[i][0], 0, 0, 0);                 \
            acc[i][1] = MFMA16(a[i], CUR[1], acc[i][1], 0, 0, 0);                 \
        }                                                                         \
        __builtin_amdgcn_s_setprio(0);                                            \
        asm volatile("s_waitcnt lgkmcnt(0)" ::: "memory");                        \
        __builtin_amdgcn_sched_barrier(0);                                        \
        __builtin_amdgcn_s_barrier();                                             \
        if ((T) + 2 < NKT2) stageA(BUF, (T) + 2);                                 \
        __builtin_amdgcn_s_setprio(1);                                            \
        _Pragma("unroll")                                                         \
        for (int i = 0; i < 8; i++) {                                             \
            acc[i][2] = MFMA16(a[i], CUR[2], acc[i][2], 0, 0, 0);                 \
            acc[i][3] = MFMA16(a[i], CUR[3], acc[i][3], 0, 0, 0);                 \
        }                                                                         \
        __builtin_amdgcn_s_setprio(0);                                            \
        if ((T) + 2 < NKT2) { asm volatile("s_waitcnt vmcnt(2)" ::: "memory"); }  \
        else                { asm volatile("s_waitcnt vmcnt(0)" ::: "memory"); }  \
        __builtin_amdgcn_sched_barrier(0);                                        \
        __builtin_amdgcn_s_barrier();                                             \
    }

#pragma unroll 1
    for (int t = 0; t < NKT2; t += 2) {
        GTILE(t,     0, bA, bB)
        GTILE(t + 1, 1, bB, bA)
    }
#undef GTILE

    if (!PROJ) {
#pragma unroll
        for (int i = 0; i < 8; i++)
#pragma unroll
            for (int rr = 0; rr < 4; rr++) {
                int row = m0 + (wr << 7) + i * 16 + q4 * 4 + rr;
                _Float16* cp = Cb + (size_t)row * QKV_OC + n0 + (wc << 6) + r16;
#pragma unroll
                for (int ct = 0; ct < 4; ct++)
                    cp[ct * 16] = (_Float16)acc[i][ct][rr];
            }
    } else {
#pragma unroll
        for (int i = 0; i < 8; i++) {
            int row = m0 + (wr << 7) + i * 16 + q4 * 4;    // multiple of 4
            int b = row / NPIX;
            int n = row - b * NPIX;                         // 196%4==0: no straddle
#pragma unroll
            for (int ct = 0; ct < 4; ct++) {
                int col = n0 + (wc << 6) + ct * 16 + r16;
                f32x4 a = acc[i][ct];
                float4 o; o.x = a[0]; o.y = a[1]; o.z = a[2]; o.w = a[3];
                *(float4*)(Cf + ((size_t)b * CIN + col) * NPIX + n) = o;
            }
        }
    }
}

// ---------------------------------------------------------------- fused attention
// R5 VERIFIED VERSION (verbatim): 512 threads = 8 waves per (b,h) block. K/V staged
// once; q-tiles split 13-over-8 waves -> max serial depth 2. LDS 109568 B.
__global__ __launch_bounds__(512) void k_attn(const _Float16* __restrict__ qkv,
                                              _Float16* __restrict__ Ot) {
    __shared__ __align__(16) _Float16 Kl[208 * 64];
    __shared__ __align__(16) _Float16 Vt[64][216];
    __shared__ __align__(16) _Float16 Pl[8][16][216];
    int tid = threadIdx.x, wave = tid >> 6, lane = tid & 63;
    int bh = blockIdx.x;
    int b = bh / NH, h = bh - b * NH;
    const _Float16* base  = qkv + (size_t)b * NPIX * QKV_OC + h * DH;  // Q
    const _Float16* kb    = base + CIN;                                 // K
    const _Float16* vbase = base + 2 * CIN;                             // V

    {
        int c8 = lane & 7;
#pragma unroll
        for (int rr = 0; rr < 4; ++rr) {
            int grp = wave + rr * 8;
            if (grp < 26) {
                int row = grp * 8 + (lane >> 3);
                const _Float16* src = kb + (size_t)row * QKV_OC + ((c8 ^ (row & 7)) << 3);
                gload16(src, Kl + row * 64 + (c8 << 3));
            }
        }
    }
    for (int task = tid; task < 208 * 8; task += 512) {
        int m = task >> 3, dc = (task & 7) * 8;
        f16x8 v = *(const f16x8*)(vbase + (size_t)m * QKV_OC + dc);
#pragma unroll
        for (int j = 0; j < 8; j++) Vt[dc + j][m] = v[j];
    }
    __syncthreads();

    int r16 = lane & 15, q4 = lane >> 4, r7 = r16 & 7;
    int kc0 = ((q4)     ^ r7) << 3;
    int kc1 = ((q4 + 4) ^ r7) << 3;
    const float s2 = 0.125f;

    for (int nt = wave; nt < 13; nt += 8) {
        f16x8 aq0 = *(const f16x8*)(base + (size_t)(nt * 16 + r16) * QKV_OC + q4 * 8);
        f16x8 aq1 = *(const f16x8*)(base + (size_t)(nt * 16 + r16) * QKV_OC + 32 + q4 * 8);
        f32x4 L[13];
#pragma unroll
        for (int mt = 0; mt < 13; ++mt) {
            const _Float16* kr = Kl + (mt * 16 + r16) * 64;
            f16x8 bk0 = *(const f16x8*)(kr + kc0);
            f16x8 bk1 = *(const f16x8*)(kr + kc1);
            f32x4 s = {0.f, 0.f, 0.f, 0.f};
            s = MFMA16(aq0, bk0, s, 0, 0, 0);
            s = MFMA16(aq1, bk1, s, 0, 0, 0);
            L[mt] = s;
        }
        float mx[4] = {-1e30f, -1e30f, -1e30f, -1e30f};
#pragma unroll
        for (int mt = 0; mt < 13; ++mt)
#pragma unroll
            for (int r = 0; r < 4; ++r) {
                float lv = L[mt][r] * s2;
                if (mt == 12 && r16 >= 4) lv = -1e30f;   // mask m >= 196
                L[mt][r] = lv;
                mx[r] = fmaxf(mx[r], lv);
            }
#pragma unroll
        for (int r = 0; r < 4; ++r)
            for (int off = 1; off < 16; off <<= 1)
                mx[r] = fmaxf(mx[r], __shfl_xor(mx[r], off));
        float sm[4] = {0.f, 0.f, 0.f, 0.f};
#pragma unroll
        for (int mt = 0; mt < 13; ++mt)
#pragma unroll
            for (int r = 0; r < 4; ++r) {
                float p = exp2f((L[mt][r] - mx[r]) * 1.44269504f);
                sm[r] += p;
                Pl[wave][q4 * 4 + r][mt * 16 + r16] = (_Float16)p;
            }
#pragma unroll
        for (int r = 0; r < 4; ++r)
            for (int off = 1; off < 16; off <<= 1)
                sm[r] += __shfl_xor(sm[r], off);

        f32x4 oacc[4];
#pragma unroll
        for (int di = 0; di < 4; ++di) oacc[di] = (f32x4){0.f, 0.f, 0.f, 0.f};
#pragma unroll
        for (int mc = 0; mc < 6; ++mc) {
            f16x8 ap = *(const f16x8*)&Pl[wave][r16][mc * 32 + q4 * 8];
#pragma unroll
            for (int di = 0; di < 4; ++di) {
                f16x8 bv = *(const f16x8*)&Vt[di * 16 + r16][mc * 32 + q4 * 8];
                oacc[di] = MFMA16(ap, bv, oacc[di], 0, 0, 0);
            }
        }
        {
            _Float16 z = (_Float16)0.f;
            f16x8 zz = (f16x8){z, z, z, z, z, z, z, z};
            f16x8 ap = (q4 < 2) ? *(const f16x8*)&Pl[wave][r16][192 + q4 * 8] : zz;
#pragma unroll
            for (int di = 0; di < 4; ++di) {
                f16x8 bv = (q4 < 2) ? *(const f16x8*)&Vt[di * 16 + r16][192 + q4 * 8] : zz;
                oacc[di] = MFMA16(ap, bv, oacc[di], 0, 0, 0);
            }
        }
#pragma unroll
        for (int r = 0; r < 4; ++r) {
            int n = nt * 16 + q4 * 4 + r;
            if (n < NPIX) {
                float rinv = 1.0f / sm[r];
                _Float16* op = Ot + (size_t)(b * NPIX + n) * CIN + h * DH + r16;
#pragma unroll
                for (int di = 0; di < 4; ++di)
                    op[di * 16] = (_Float16)(oacc[di][r] * rinv);
            }
        }
    }
}

// ---------------------------------------------------------------- launch
extern "C" void kernel_launch(void* const* d_in, const int* in_sizes, int n_in,
                              void* d_out, int out_size, void* d_ws, size_t ws_size,
                              hipStream_t stream) {
    const float* x  = (const float*)d_in[0];
    const float* wq = (const float*)d_in[1];
    const float* wp = (const float*)d_in[2];
    float* out = (float*)d_out;
    char* ws = (char*)d_ws;

    _Float16* Xt  = (_Float16*)(ws);
    _Float16* W   = (_Float16*)(ws + 20447232);
    _Float16* qkv = (_Float16*)(ws + 25165824);
    _Float16* Ot  = (_Float16*)(ws + 86507520);
    _Float16* Wq = W;
    _Float16* Wp = W + (size_t)QKV_OC * CIN;

    hipLaunchKernelGGL(k_convert_w, dim3(2304), dim3(256), 0, stream, wq, wp, W);
    hipLaunchKernelGGL(k_transpose_x, dim3(12, 64), dim3(256), 0, stream, x, Xt);
    hipLaunchKernelGGL((k_gemm2<9, false>), dim3(49 * 9), dim3(512), 0, stream,
                       Xt, Wq, qkv, (float*)nullptr);
    hipLaunchKernelGGL(k_attn, dim3(768), dim3(512), 0, stream, qkv, Ot);
    hipLaunchKernelGGL((k_gemm2<3, true>), dim3(49 * 3), dim3(512), 0, stream,
                       Ot, Wp, (_Float16*)nullptr, out);
}

// Round 8
// 145.198 us; speedup vs baseline: 1.2841x; 1.2242x over previous
//
#include <hip/hip_runtime.h>
#include <cstdint>
#include <cstddef>

#define NH     12
#define DH     64
#define CIN    768
#define NPIX   196
#define NB     64
#define ROWS   (NB * NPIX)      // 12544
#define QKV_OC 2304
#define NKT    12               // 768/64

typedef __attribute__((ext_vector_type(8))) _Float16 f16x8;
typedef __attribute__((ext_vector_type(4))) _Float16 f16x4;
typedef __attribute__((ext_vector_type(4))) float    f32x4;

#define MFMA16 __builtin_amdgcn_mfma_f32_16x16x32_f16

// ---------------------------------------------------------------- weights → fp16
__global__ __launch_bounds__(256) void k_convert_w(const float* __restrict__ wq,
                                                   const float* __restrict__ wp,
                                                   _Float16* __restrict__ out) {
    int i = blockIdx.x * 256 + threadIdx.x;
    const int NQ = QKV_OC * CIN / 4;
    const int NT = NQ + (CIN * CIN) / 4;
    if (i >= NT) return;
    float4 v = (i < NQ) ? ((const float4*)wq)[i] : ((const float4*)wp)[i - NQ];
    f16x4 o = { (_Float16)v.x, (_Float16)v.y, (_Float16)v.z, (_Float16)v.w };
    ((f16x4*)out)[i] = o;
}

// ------------------------------------------------- x [b][c][n] f32 → Xt [b*196+n][c] f16
__global__ __launch_bounds__(256) void k_transpose_x(const float* __restrict__ x,
                                                     _Float16* __restrict__ Xt) {
    __shared__ __align__(16) _Float16 lds[NPIX][72];
    int t  = threadIdx.x;
    int b  = blockIdx.y, c0 = blockIdx.x * 64;
    const float* xp = x + ((size_t)b * CIN + c0) * NPIX;
    for (int idx = t; idx < 64 * 49; idx += 256) {
        int c = idx / 49, k = idx - c * 49;
        float4 v = *(const float4*)(xp + (size_t)c * NPIX + k * 4);
        int n = k * 4;
        lds[n][c]     = (_Float16)v.x;
        lds[n + 1][c] = (_Float16)v.y;
        lds[n + 2][c] = (_Float16)v.z;
        lds[n + 3][c] = (_Float16)v.w;
    }
    __syncthreads();
    int cs = t & 7, nn = t >> 3;
    for (int n = nn; n < NPIX; n += 32) {
        _Float16* dst = Xt + ((size_t)(b * NPIX + n)) * CIN + c0 + cs * 8;
        *(ulonglong2*)dst = *(const ulonglong2*)&lds[n][cs * 8];
    }
}

// ---------------------------------------------------------------- helpers
__device__ inline void gload16(const _Float16* g, _Float16* l) {
    __builtin_amdgcn_global_load_lds((const __attribute__((address_space(1))) void*)g,
                                     (__attribute__((address_space(3))) void*)l,
                                     16, 0, 0);
}

// ---------------------------------------------------------------- 128x128 2-barrier GEMM
// R0 proven skeleton re-parameterized to 128² (guide tile-space: 128² > 256² at this
// structure, m103 912 vs 792 TF). 256 thr = 4 waves (2x2), wave tile 64x64, BK=64.
// acc 64 AGPR + ~100 VGPR ≈ 164 (m97's budget) -> no spill; LDS 64 KiB -> 2 blocks/CU.
// Identical sync choreography, swizzle involution, and vmcnt arithmetic as R0
// (8 staging loads per tile: prologue vmcnt(8); loop vmcnt(8)/vmcnt(0)).
// C[r][o] = sum_c A[r][c]*B[o][c]; A:[12544][768], B:[NTN*128][768]
// PROJ=false: C f16 [row][2304];  PROJ=true: Cf f32 out[b][col][n]
template<int NTN, bool PROJ>
__global__ __launch_bounds__(256, 2) void k_gemm2(const _Float16* __restrict__ A,
                                                  const _Float16* __restrict__ Bm,
                                                  _Float16* __restrict__ Cb,
                                                  float* __restrict__ Cf) {
    __shared__ __align__(16) _Float16 As[2][128 * 64];   // 16 KiB per buf
    __shared__ __align__(16) _Float16 Bs[2][128 * 64];   // total 64 KiB
    int tid = threadIdx.x;
    int w = tid >> 6, lane = tid & 63;

    // T1: bijective XCD swizzle
    int nwg = gridDim.x;
    int orig = blockIdx.x;
    int q = nwg >> 3, r = nwg & 7;
    int xcd = orig & 7, within = orig >> 3;
    int wg = (xcd < r ? xcd * (q + 1) : r * (q + 1) + (xcd - r) * q) + within;
    int bm = wg / NTN, bn = wg - bm * NTN;
    int m0 = bm * 128, n0 = bn * 128;

    int wr = w >> 1, wc = w & 1;          // 2 x 2 wave grid, wave tile 64x64
    int r16 = lane & 15, q4 = lane >> 4;

    // staging (T2: inverse-swizzled global source; linear LDS dest)
    // rows per sweep: 256 thr / 8 lanes-per-row = 32; 4 sweeps cover 128 rows.
    int sr8  = (w << 3) + (lane >> 3);                    // 0..31
    int swz8 = ((lane & 7) ^ (lane >> 3)) << 3;           // chunk ^ (row&7)
    const _Float16* Ag = A  + (size_t)(m0 + sr8) * CIN + swz8;
    const _Float16* Bg = Bm + (size_t)(n0 + sr8) * CIN + swz8;

    auto stageA = [&](int buf, int kt) {
        const _Float16* g = Ag + kt * 64;
        _Float16* l0 = As[buf] + (w << 9);                // w*8 rows * 64
        gload16(g,            l0);
        gload16(g + 32 * CIN, l0 + 2048);
        gload16(g + 64 * CIN, l0 + 4096);
        gload16(g + 96 * CIN, l0 + 6144);
    };
    auto stageB = [&](int buf, int kt) {
        const _Float16* g = Bg + kt * 64;
        _Float16* l0 = Bs[buf] + (w << 9);
        gload16(g,            l0);
        gload16(g + 32 * CIN, l0 + 2048);
        gload16(g + 64 * CIN, l0 + 4096);
        gload16(g + 96 * CIN, l0 + 6144);
    };

    int cS0 = ((q4)     ^ (r16 & 7)) << 3;
    int cS1 = ((q4 + 4) ^ (r16 & 7)) << 3;

    f32x4 acc[4][4];
#pragma unroll
    for (int i = 0; i < 4; i++)
#pragma unroll
        for (int j = 0; j < 4; j++) acc[i][j] = (f32x4){0.f, 0.f, 0.f, 0.f};

    // prologue: stage tiles 0 and 1 (8 loads each); vmcnt(8) drains tile 0
    stageA(0, 0); stageB(0, 0);
    stageA(1, 1); stageB(1, 1);
    asm volatile("s_waitcnt vmcnt(8)" ::: "memory");
    __builtin_amdgcn_sched_barrier(0);
    __builtin_amdgcn_s_barrier();

#pragma unroll 2
    for (int t = 0; t < NKT; ++t) {
        int bt = t & 1;
        const _Float16* Ab = As[bt] + ((wr << 6) + r16) * 64;
        const _Float16* Bb = Bs[bt] + ((wc << 6) + r16) * 64;
        bool pre = (t + 2 < NKT);

        // 16 x ds_read_b128: full fragment set for this K-tile
        f16x8 a[4][2], b[4][2];
#pragma unroll
        for (int i = 0; i < 4; i++) {
            a[i][0] = *(const f16x8*)(Ab + (i << 10) + cS0);
            a[i][1] = *(const f16x8*)(Ab + (i << 10) + cS1);
        }
#pragma unroll
        for (int j = 0; j < 4; j++) {
            b[j][0] = *(const f16x8*)(Bb + (j << 10) + cS0);
            b[j][1] = *(const f16x8*)(Bb + (j << 10) + cS1);
        }

        // MFMA burst 1: cols 0,1 (compiler inserts fine-grained lgkm waits)
        __builtin_amdgcn_s_setprio(1);
#pragma unroll
        for (int i = 0; i < 4; i++)
#pragma unroll
            for (int j = 0; j < 2; j++) {
                acc[i][j] = MFMA16(a[i][0], b[j][0], acc[i][j], 0, 0, 0);
                acc[i][j] = MFMA16(a[i][1], b[j][1], acc[i][j], 0, 0, 0);
            }
        __builtin_amdgcn_s_setprio(0);

        // all 16 reads complete for every wave at this barrier
        asm volatile("s_waitcnt lgkmcnt(0)" ::: "memory");
        __builtin_amdgcn_sched_barrier(0);
        __builtin_amdgcn_s_barrier();

        // stage tile t+2 into the buffer we just finished reading
        if (pre) { stageA(bt, t + 2); stageB(bt, t + 2); }

        // MFMA burst 2: cols 2,3
        __builtin_amdgcn_s_setprio(1);
#pragma unroll
        for (int i = 0; i < 4; i++)
#pragma unroll
            for (int j = 2; j < 4; j++) {
                acc[i][j] = MFMA16(a[i][0], b[j][0], acc[i][j], 0, 0, 0);
                acc[i][j] = MFMA16(a[i][1], b[j][1], acc[i][j], 0, 0, 0);
            }
        __builtin_amdgcn_s_setprio(0);

        // tile t+1 must be resident before next iteration's reads
        if (pre) { asm volatile("s_waitcnt vmcnt(8)" ::: "memory"); }
        else     { asm volatile("s_waitcnt vmcnt(0)" ::: "memory"); }
        __builtin_amdgcn_sched_barrier(0);
        __builtin_amdgcn_s_barrier();
    }

    if (!PROJ) {
#pragma unroll
        for (int i = 0; i < 4; i++)
#pragma unroll
            for (int rr = 0; rr < 4; rr++) {
                int row = m0 + (wr << 6) + i * 16 + q4 * 4 + rr;
                _Float16* cp = Cb + (size_t)row * QKV_OC + n0 + (wc << 6) + r16;
#pragma unroll
                for (int ct = 0; ct < 4; ct++)
                    cp[ct * 16] = (_Float16)acc[i][ct][rr];
            }
    } else {
#pragma unroll
        for (int i = 0; i < 4; i++) {
            int row = m0 + (wr << 6) + i * 16 + q4 * 4;    // multiple of 4
            int b = row / NPIX;
            int n = row - b * NPIX;                         // 196%4==0: no straddle
#pragma unroll
            for (int ct = 0; ct < 4; ct++) {
                int col = n0 + (wc << 6) + ct * 16 + r16;
                f32x4 a = acc[i][ct];
                float4 o; o.x = a[0]; o.y = a[1]; o.z = a[2]; o.w = a[3];
                *(float4*)(Cf + ((size_t)b * CIN + col) * NPIX + n) = o;
            }
        }
    }
}

// ---------------------------------------------------------------- fused attention
// R5 VERIFIED VERSION (verbatim): 512 threads = 8 waves per (b,h) block. K/V staged
// once; q-tiles split 13-over-8 waves -> max serial depth 2. LDS 109568 B.
__global__ __launch_bounds__(512) void k_attn(const _Float16* __restrict__ qkv,
                                              _Float16* __restrict__ Ot) {
    __shared__ __align__(16) _Float16 Kl[208 * 64];
    __shared__ __align__(16) _Float16 Vt[64][216];
    __shared__ __align__(16) _Float16 Pl[8][16][216];
    int tid = threadIdx.x, wave = tid >> 6, lane = tid & 63;
    int bh = blockIdx.x;
    int b = bh / NH, h = bh - b * NH;
    const _Float16* base  = qkv + (size_t)b * NPIX * QKV_OC + h * DH;  // Q
    const _Float16* kb    = base + CIN;                                 // K
    const _Float16* vbase = base + 2 * CIN;                             // V

    {
        int c8 = lane & 7;
#pragma unroll
        for (int rr = 0; rr < 4; ++rr) {
            int grp = wave + rr * 8;
            if (grp < 26) {
                int row = grp * 8 + (lane >> 3);
                const _Float16* src = kb + (size_t)row * QKV_OC + ((c8 ^ (row & 7)) << 3);
                gload16(src, Kl + row * 64 + (c8 << 3));
            }
        }
    }
    for (int task = tid; task < 208 * 8; task += 512) {
        int m = task >> 3, dc = (task & 7) * 8;
        f16x8 v = *(const f16x8*)(vbase + (size_t)m * QKV_OC + dc);
#pragma unroll
        for (int j = 0; j < 8; j++) Vt[dc + j][m] = v[j];
    }
    __syncthreads();

    int r16 = lane & 15, q4 = lane >> 4, r7 = r16 & 7;
    int kc0 = ((q4)     ^ r7) << 3;
    int kc1 = ((q4 + 4) ^ r7) << 3;
    const float s2 = 0.125f;

    for (int nt = wave; nt < 13; nt += 8) {
        f16x8 aq0 = *(const f16x8*)(base + (size_t)(nt * 16 + r16) * QKV_OC + q4 * 8);
        f16x8 aq1 = *(const f16x8*)(base + (size_t)(nt * 16 + r16) * QKV_OC + 32 + q4 * 8);
        f32x4 L[13];
#pragma unroll
        for (int mt = 0; mt < 13; ++mt) {
            const _Float16* kr = Kl + (mt * 16 + r16) * 64;
            f16x8 bk0 = *(const f16x8*)(kr + kc0);
            f16x8 bk1 = *(const f16x8*)(kr + kc1);
            f32x4 s = {0.f, 0.f, 0.f, 0.f};
            s = MFMA16(aq0, bk0, s, 0, 0, 0);
            s = MFMA16(aq1, bk1, s, 0, 0, 0);
            L[mt] = s;
        }
        float mx[4] = {-1e30f, -1e30f, -1e30f, -1e30f};
#pragma unroll
        for (int mt = 0; mt < 13; ++mt)
#pragma unroll
            for (int r = 0; r < 4; ++r) {
                float lv = L[mt][r] * s2;
                if (mt == 12 && r16 >= 4) lv = -1e30f;   // mask m >= 196
                L[mt][r] = lv;
                mx[r] = fmaxf(mx[r], lv);
            }
#pragma unroll
        for (int r = 0; r < 4; ++r)
            for (int off = 1; off < 16; off <<= 1)
                mx[r] = fmaxf(mx[r], __shfl_xor(mx[r], off));
        float sm[4] = {0.f, 0.f, 0.f, 0.f};
#pragma unroll
        for (int mt = 0; mt < 13; ++mt)
#pragma unroll
            for (int r = 0; r < 4; ++r) {
                float p = exp2f((L[mt][r] - mx[r]) * 1.44269504f);
                sm[r] += p;
                Pl[wave][q4 * 4 + r][mt * 16 + r16] = (_Float16)p;
            }
#pragma unroll
        for (int r = 0; r < 4; ++r)
            for (int off = 1; off < 16; off <<= 1)
                sm[r] += __shfl_xor(sm[r], off);

        f32x4 oacc[4];
#pragma unroll
        for (int di = 0; di < 4; ++di) oacc[di] = (f32x4){0.f, 0.f, 0.f, 0.f};
#pragma unroll
        for (int mc = 0; mc < 6; ++mc) {
            f16x8 ap = *(const f16x8*)&Pl[wave][r16][mc * 32 + q4 * 8];
#pragma unroll
            for (int di = 0; di < 4; ++di) {
                f16x8 bv = *(const f16x8*)&Vt[di * 16 + r16][mc * 32 + q4 * 8];
                oacc[di] = MFMA16(ap, bv, oacc[di], 0, 0, 0);
            }
        }
        {
            _Float16 z = (_Float16)0.f;
            f16x8 zz = (f16x8){z, z, z, z, z, z, z, z};
            f16x8 ap = (q4 < 2) ? *(const f16x8*)&Pl[wave][r16][192 + q4 * 8] : zz;
#pragma unroll
            for (int di = 0; di < 4; ++di) {
                f16x8 bv = (q4 < 2) ? *(const f16x8*)&Vt[di * 16 + r16][192 + q4 * 8] : zz;
                oacc[di] = MFMA16(ap, bv, oacc[di], 0, 0, 0);
            }
        }
#pragma unroll
        for (int r = 0; r < 4; ++r) {
            int n = nt * 16 + q4 * 4 + r;
            if (n < NPIX) {
                float rinv = 1.0f / sm[r];
                _Float16* op = Ot + (size_t)(b * NPIX + n) * CIN + h * DH + r16;
#pragma unroll
                for (int di = 0; di < 4; ++di)
                    op[di * 16] = (_Float16)(oacc[di][r] * rinv);
            }
        }
    }
}

// ---------------------------------------------------------------- launch
extern "C" void kernel_launch(void* const* d_in, const int* in_sizes, int n_in,
                              void* d_out, int out_size, void* d_ws, size_t ws_size,
                              hipStream_t stream) {
    const float* x  = (const float*)d_in[0];
    const float* wq = (const float*)d_in[1];
    const float* wp = (const float*)d_in[2];
    float* out = (float*)d_out;
    char* ws = (char*)d_ws;

    _Float16* Xt  = (_Float16*)(ws);
    _Float16* W   = (_Float16*)(ws + 20447232);
    _Float16* qkv = (_Float16*)(ws + 25165824);
    _Float16* Ot  = (_Float16*)(ws + 86507520);
    _Float16* Wq = W;
    _Float16* Wp = W + (size_t)QKV_OC * CIN;

    hipLaunchKernelGGL(k_convert_w, dim3(2304), dim3(256), 0, stream, wq, wp, W);
    hipLaunchKernelGGL(k_transpose_x, dim3(12, 64), dim3(256), 0, stream, x, Xt);
    hipLaunchKernelGGL((k_gemm2<18, false>), dim3(98 * 18), dim3(256), 0, stream,
                       Xt, Wq, qkv, (float*)nullptr);
    hipLaunchKernelGGL(k_attn, dim3(768), dim3(512), 0, stream, qkv, Ot);
    hipLaunchKernelGGL((k_gemm2<6, true>), dim3(98 * 6), dim3(256), 0, stream,
                       Ot, Wp, (_Float16*)nullptr, out);
}

// Round 9
// 133.915 us; speedup vs baseline: 1.3923x; 1.0843x over previous
//
#include <hip/hip_runtime.h>
#include <cstdint>
#include <cstddef>

#define NH     12
#define DH     64
#define CIN    768
#define NPIX   196
#define NB     64
#define ROWS   (NB * NPIX)      // 12544
#define QKV_OC 2304
#define NKT    12               // 768/64

typedef __attribute__((ext_vector_type(8))) _Float16 f16x8;
typedef __attribute__((ext_vector_type(4))) _Float16 f16x4;
typedef __attribute__((ext_vector_type(4))) float    f32x4;

#define MFMA16 __builtin_amdgcn_mfma_f32_16x16x32_f16

// ---------------------------------------------------------------- weights → fp16
__global__ __launch_bounds__(256) void k_convert_w(const float* __restrict__ wq,
                                                   const float* __restrict__ wp,
                                                   _Float16* __restrict__ out) {
    int i = blockIdx.x * 256 + threadIdx.x;
    const int NQ = QKV_OC * CIN / 4;
    const int NT = NQ + (CIN * CIN) / 4;
    if (i >= NT) return;
    float4 v = (i < NQ) ? ((const float4*)wq)[i] : ((const float4*)wp)[i - NQ];
    f16x4 o = { (_Float16)v.x, (_Float16)v.y, (_Float16)v.z, (_Float16)v.w };
    ((f16x4*)out)[i] = o;
}

// ------------------------------------------------- x [b][c][n] f32 → Xt [b*196+n][c] f16
__global__ __launch_bounds__(256) void k_transpose_x(const float* __restrict__ x,
                                                     _Float16* __restrict__ Xt) {
    __shared__ __align__(16) _Float16 lds[NPIX][72];
    int t  = threadIdx.x;
    int b  = blockIdx.y, c0 = blockIdx.x * 64;
    const float* xp = x + ((size_t)b * CIN + c0) * NPIX;
    for (int idx = t; idx < 64 * 49; idx += 256) {
        int c = idx / 49, k = idx - c * 49;
        float4 v = *(const float4*)(xp + (size_t)c * NPIX + k * 4);
        int n = k * 4;
        lds[n][c]     = (_Float16)v.x;
        lds[n + 1][c] = (_Float16)v.y;
        lds[n + 2][c] = (_Float16)v.z;
        lds[n + 3][c] = (_Float16)v.w;
    }
    __syncthreads();
    int cs = t & 7, nn = t >> 3;
    for (int n = nn; n < NPIX; n += 32) {
        _Float16* dst = Xt + ((size_t)(b * NPIX + n)) * CIN + c0 + cs * 8;
        *(ulonglong2*)dst = *(const ulonglong2*)&lds[n][cs * 8];
    }
}

// ---------------------------------------------------------------- helpers
__device__ inline void gload16(const _Float16* g, _Float16* l) {
    __builtin_amdgcn_global_load_lds((const __attribute__((address_space(1))) void*)g,
                                     (__attribute__((address_space(3))) void*)l,
                                     16, 0, 0);
}

// ---------------------------------------------------------------- 256x256 2-barrier GEMM
// R0 BEST-VERIFIED VERSION (verbatim; frozen — 6 variants tested, all worse).
// 512 thr, 8 waves, BK=64. C[r][o] = sum_c A[r][c]*B[o][c].
// PROJ=false: C f16 [row][2304];  PROJ=true: Cf f32 out[b][col][n]
template<int NTN, bool PROJ>
__global__ __launch_bounds__(512, 2) void k_gemm2(const _Float16* __restrict__ A,
                                                  const _Float16* __restrict__ Bm,
                                                  _Float16* __restrict__ Cb,
                                                  float* __restrict__ Cf) {
    __shared__ __align__(16) _Float16 As[2][256 * 64];   // 64 KiB
    __shared__ __align__(16) _Float16 Bs[2][256 * 64];   // 64 KiB
    int tid = threadIdx.x;
    int w = tid >> 6, lane = tid & 63;

    // T1: bijective XCD swizzle
    int nwg = gridDim.x;
    int orig = blockIdx.x;
    int q = nwg >> 3, r = nwg & 7;
    int xcd = orig & 7, within = orig >> 3;
    int wg = (xcd < r ? xcd * (q + 1) : r * (q + 1) + (xcd - r) * q) + within;
    int bm = wg / NTN, bn = wg - bm * NTN;
    int m0 = bm * 256, n0 = bn * 256;

    int wr = w >> 2, wc = w & 3;          // 2 x 4 wave grid
    int r16 = lane & 15, q4 = lane >> 4;

    // staging (T2: inverse-swizzled global source; linear LDS dest)
    int sr8  = (w << 3) + (lane >> 3);                    // 0..63
    int swz8 = ((lane & 7) ^ (lane >> 3)) << 3;
    const _Float16* Ag = A  + (size_t)(m0 + sr8) * CIN + swz8;
    const _Float16* Bg = Bm + (size_t)(n0 + sr8) * CIN + swz8;

    auto stageA = [&](int buf, int kt) {
        const _Float16* g = Ag + kt * 64;
        _Float16* l0 = As[buf] + (w << 9);
        gload16(g,             l0);
        gload16(g +  64 * CIN, l0 + 4096);
        gload16(g + 128 * CIN, l0 + 8192);
        gload16(g + 192 * CIN, l0 + 12288);
    };
    auto stageB = [&](int buf, int kt) {
        const _Float16* g = Bg + kt * 64;
        _Float16* l0 = Bs[buf] + (w << 9);
        gload16(g,             l0);
        gload16(g +  64 * CIN, l0 + 4096);
        gload16(g + 128 * CIN, l0 + 8192);
        gload16(g + 192 * CIN, l0 + 12288);
    };

    int cS0 = ((q4)     ^ (r16 & 7)) << 3;
    int cS1 = ((q4 + 4) ^ (r16 & 7)) << 3;

    f32x4 acc[8][4];
#pragma unroll
    for (int i = 0; i < 8; i++)
#pragma unroll
        for (int j = 0; j < 4; j++) acc[i][j] = (f32x4){0.f, 0.f, 0.f, 0.f};

    // prologue
    stageA(0, 0); stageB(0, 0);
    stageA(1, 1); stageB(1, 1);
    asm volatile("s_waitcnt vmcnt(8)" ::: "memory");
    __builtin_amdgcn_sched_barrier(0);
    __builtin_amdgcn_s_barrier();

#pragma unroll 2
    for (int t = 0; t < NKT; ++t) {
        int bt = t & 1;
        const _Float16* Ab = As[bt] + ((wr << 7) + r16) * 64;
        const _Float16* Bb = Bs[bt] + ((wc << 6) + r16) * 64;
        bool pre = (t + 2 < NKT);

        // read all fragments for this K-tile (24 x ds_read_b128)
        f16x8 a0[4][2], a1[4][2], b0[2][2], b1[2][2];
#pragma unroll
        for (int i = 0; i < 4; i++) {
            a0[i][0] = *(const f16x8*)(Ab + (i << 10) + cS0);
            a0[i][1] = *(const f16x8*)(Ab + (i << 10) + cS1);
            a1[i][0] = *(const f16x8*)(Ab + 4096 + (i << 10) + cS0);
            a1[i][1] = *(const f16x8*)(Ab + 4096 + (i << 10) + cS1);
        }
#pragma unroll
        for (int j = 0; j < 2; j++) {
            b0[j][0] = *(const f16x8*)(Bb + (j << 10) + cS0);
            b0[j][1] = *(const f16x8*)(Bb + (j << 10) + cS1);
            b1[j][0] = *(const f16x8*)(Bb + 2048 + (j << 10) + cS0);
            b1[j][1] = *(const f16x8*)(Bb + 2048 + (j << 10) + cS1);
        }

        // MFMA burst 1: all x b0  (compiler inserts fine-grained lgkm waits)
        __builtin_amdgcn_s_setprio(1);
#pragma unroll
        for (int i = 0; i < 4; i++)
#pragma unroll
            for (int j = 0; j < 2; j++) {
                acc[i][j]     = MFMA16(a0[i][0], b0[j][0], acc[i][j],     0, 0, 0);
                acc[i][j]     = MFMA16(a0[i][1], b0[j][1], acc[i][j],     0, 0, 0);
                acc[4 + i][j] = MFMA16(a1[i][0], b0[j][0], acc[4 + i][j], 0, 0, 0);
                acc[4 + i][j] = MFMA16(a1[i][1], b0[j][1], acc[4 + i][j], 0, 0, 0);
            }
        __builtin_amdgcn_s_setprio(0);

        // all 24 reads complete for every wave at this barrier
        asm volatile("s_waitcnt lgkmcnt(0)" ::: "memory");
        __builtin_amdgcn_sched_barrier(0);
        __builtin_amdgcn_s_barrier();

        // stage tile t+2 into the buffer we just finished reading
        if (pre) { stageA(bt, t + 2); stageB(bt, t + 2); }

        // MFMA burst 2: all x b1
        __builtin_amdgcn_s_setprio(1);
#pragma unroll
        for (int i = 0; i < 4; i++)
#pragma unroll
            for (int j = 0; j < 2; j++) {
                acc[i][2 + j]     = MFMA16(a0[i][0], b1[j][0], acc[i][2 + j],     0, 0, 0);
                acc[i][2 + j]     = MFMA16(a0[i][1], b1[j][1], acc[i][2 + j],     0, 0, 0);
                acc[4 + i][2 + j] = MFMA16(a1[i][0], b1[j][0], acc[4 + i][2 + j], 0, 0, 0);
                acc[4 + i][2 + j] = MFMA16(a1[i][1], b1[j][1], acc[4 + i][2 + j], 0, 0, 0);
            }
        __builtin_amdgcn_s_setprio(0);

        // tile t+1 must be resident before next iteration's reads
        if (pre) { asm volatile("s_waitcnt vmcnt(8)" ::: "memory"); }
        else     { asm volatile("s_waitcnt vmcnt(0)" ::: "memory"); }
        __builtin_amdgcn_sched_barrier(0);
        __builtin_amdgcn_s_barrier();
    }

    if (!PROJ) {
#pragma unroll
        for (int hh = 0; hh < 2; hh++)
#pragma unroll
            for (int i = 0; i < 4; i++)
#pragma unroll
                for (int rr = 0; rr < 4; rr++) {
                    int row = m0 + (wr << 7) + hh * 64 + i * 16 + q4 * 4 + rr;
                    _Float16* cp = Cb + (size_t)row * QKV_OC + n0 + (wc << 6) + r16;
#pragma unroll
                    for (int g = 0; g < 2; g++)
#pragma unroll
                        for (int j = 0; j < 2; j++)
                            cp[g * 32 + j * 16] = (_Float16)acc[hh * 4 + i][g * 2 + j][rr];
                }
    } else {
#pragma unroll
        for (int hh = 0; hh < 2; hh++)
#pragma unroll
            for (int i = 0; i < 4; i++) {
                int row = m0 + (wr << 7) + hh * 64 + i * 16 + q4 * 4;  // mult of 4
                int b = row / NPIX;
                int n = row - b * NPIX;                                 // 196%4==0: no straddle
#pragma unroll
                for (int g = 0; g < 2; g++)
#pragma unroll
                    for (int j = 0; j < 2; j++) {
                        int col = n0 + (wc << 6) + g * 32 + j * 16 + r16;
                        f32x4 a = acc[hh * 4 + i][g * 2 + j];
                        float4 o; o.x = a[0]; o.y = a[1]; o.z = a[2]; o.w = a[3];
                        *(float4*)(Cf + ((size_t)b * CIN + col) * NPIX + n) = o;
                    }
            }
    }
}

// ---------------------------------------------------------------- fused attention
// 832 threads = 13 waves per (b,h) block: ONE q-tile per wave (serial depth 1,
// was 2 for 5-of-8 waves in R5) and 3.25 waves/SIMD (was 2). Staging counts fall
// out exactly: K 26 row-groups = 13 waves x 2; V 1664 tasks = 832 x 2.
// LDS: Kl 26624 + Vt 27648 + Pl[13] 89856 = 144128 B <= 160 KiB, 1 block/CU
// (unchanged). Same single __syncthreads; per-wave work independent; grid 768
// = 3 exact rounds.
__global__ __launch_bounds__(832) void k_attn(const _Float16* __restrict__ qkv,
                                              _Float16* __restrict__ Ot) {
    __shared__ __align__(16) _Float16 Kl[208 * 64];
    __shared__ __align__(16) _Float16 Vt[64][216];
    __shared__ __align__(16) _Float16 Pl[13][16][216];
    int tid = threadIdx.x, wave = tid >> 6, lane = tid & 63;
    int bh = blockIdx.x;
    int b = bh / NH, h = bh - b * NH;
    const _Float16* base  = qkv + (size_t)b * NPIX * QKV_OC + h * DH;  // Q
    const _Float16* kb    = base + CIN;                                 // K
    const _Float16* vbase = base + 2 * CIN;                             // V

    {
        int c8 = lane & 7;
#pragma unroll
        for (int rr = 0; rr < 2; ++rr) {
            int grp = wave + rr * 13;                       // 0..25 exactly
            int row = grp * 8 + (lane >> 3);
            const _Float16* src = kb + (size_t)row * QKV_OC + ((c8 ^ (row & 7)) << 3);
            gload16(src, Kl + row * 64 + (c8 << 3));
        }
    }
    for (int task = tid; task < 208 * 8; task += 832) {    // 2 iterations exactly
        int m = task >> 3, dc = (task & 7) * 8;
        f16x8 v = *(const f16x8*)(vbase + (size_t)m * QKV_OC + dc);
#pragma unroll
        for (int j = 0; j < 8; j++) Vt[dc + j][m] = v[j];
    }
    __syncthreads();

    int r16 = lane & 15, q4 = lane >> 4, r7 = r16 & 7;
    int kc0 = ((q4)     ^ r7) << 3;
    int kc1 = ((q4 + 4) ^ r7) << 3;
    const float s2 = 0.125f;

    {
        int nt = wave;                                     // one q-tile per wave
        f16x8 aq0 = *(const f16x8*)(base + (size_t)(nt * 16 + r16) * QKV_OC + q4 * 8);
        f16x8 aq1 = *(const f16x8*)(base + (size_t)(nt * 16 + r16) * QKV_OC + 32 + q4 * 8);
        f32x4 L[13];
#pragma unroll
        for (int mt = 0; mt < 13; ++mt) {
            const _Float16* kr = Kl + (mt * 16 + r16) * 64;
            f16x8 bk0 = *(const f16x8*)(kr + kc0);
            f16x8 bk1 = *(const f16x8*)(kr + kc1);
            f32x4 s = {0.f, 0.f, 0.f, 0.f};
            s = MFMA16(aq0, bk0, s, 0, 0, 0);
            s = MFMA16(aq1, bk1, s, 0, 0, 0);
            L[mt] = s;
        }
        float mx[4] = {-1e30f, -1e30f, -1e30f, -1e30f};
#pragma unroll
        for (int mt = 0; mt < 13; ++mt)
#pragma unroll
            for (int r = 0; r < 4; ++r) {
                float lv = L[mt][r] * s2;
                if (mt == 12 && r16 >= 4) lv = -1e30f;   // mask m >= 196
                L[mt][r] = lv;
                mx[r] = fmaxf(mx[r], lv);
            }
#pragma unroll
        for (int r = 0; r < 4; ++r)
            for (int off = 1; off < 16; off <<= 1)
                mx[r] = fmaxf(mx[r], __shfl_xor(mx[r], off));
        float sm[4] = {0.f, 0.f, 0.f, 0.f};
#pragma unroll
        for (int mt = 0; mt < 13; ++mt)
#pragma unroll
            for (int r = 0; r < 4; ++r) {
                float p = exp2f((L[mt][r] - mx[r]) * 1.44269504f);
                sm[r] += p;
                Pl[wave][q4 * 4 + r][mt * 16 + r16] = (_Float16)p;
            }
#pragma unroll
        for (int r = 0; r < 4; ++r)
            for (int off = 1; off < 16; off <<= 1)
                sm[r] += __shfl_xor(sm[r], off);

        f32x4 oacc[4];
#pragma unroll
        for (int di = 0; di < 4; ++di) oacc[di] = (f32x4){0.f, 0.f, 0.f, 0.f};
#pragma unroll
        for (int mc = 0; mc < 6; ++mc) {
            f16x8 ap = *(const f16x8*)&Pl[wave][r16][mc * 32 + q4 * 8];
#pragma unroll
            for (int di = 0; di < 4; ++di) {
                f16x8 bv = *(const f16x8*)&Vt[di * 16 + r16][mc * 32 + q4 * 8];
                oacc[di] = MFMA16(ap, bv, oacc[di], 0, 0, 0);
            }
        }
        {
            _Float16 z = (_Float16)0.f;
            f16x8 zz = (f16x8){z, z, z, z, z, z, z, z};
            f16x8 ap = (q4 < 2) ? *(const f16x8*)&Pl[wave][r16][192 + q4 * 8] : zz;
#pragma unroll
            for (int di = 0; di < 4; ++di) {
                f16x8 bv = (q4 < 2) ? *(const f16x8*)&Vt[di * 16 + r16][192 + q4 * 8] : zz;
                oacc[di] = MFMA16(ap, bv, oacc[di], 0, 0, 0);
            }
        }
#pragma unroll
        for (int r = 0; r < 4; ++r) {
            int n = nt * 16 + q4 * 4 + r;
            if (n < NPIX) {
                float rinv = 1.0f / sm[r];
                _Float16* op = Ot + (size_t)(b * NPIX + n) * CIN + h * DH + r16;
#pragma unroll
                for (int di = 0; di < 4; ++di)
                    op[di * 16] = (_Float16)(oacc[di][r] * rinv);
            }
        }
    }
}

// ---------------------------------------------------------------- launch
extern "C" void kernel_launch(void* const* d_in, const int* in_sizes, int n_in,
                              void* d_out, int out_size, void* d_ws, size_t ws_size,
                              hipStream_t stream) {
    const float* x  = (const float*)d_in[0];
    const float* wq = (const float*)d_in[1];
    const float* wp = (const float*)d_in[2];
    float* out = (float*)d_out;
    char* ws = (char*)d_ws;

    _Float16* Xt  = (_Float16*)(ws);
    _Float16* W   = (_Float16*)(ws + 20447232);
    _Float16* qkv = (_Float16*)(ws + 25165824);
    _Float16* Ot  = (_Float16*)(ws + 86507520);
    _Float16* Wq = W;
    _Float16* Wp = W + (size_t)QKV_OC * CIN;

    hipLaunchKernelGGL(k_convert_w, dim3(2304), dim3(256), 0, stream, wq, wp, W);
    hipLaunchKernelGGL(k_transpose_x, dim3(12, 64), dim3(256), 0, stream, x, Xt);
    hipLaunchKernelGGL((k_gemm2<9, false>), dim3(49 * 9), dim3(512), 0, stream,
                       Xt, Wq, qkv, (float*)nullptr);
    hipLaunchKernelGGL(k_attn, dim3(768), dim3(832), 0, stream, qkv, Ot);
    hipLaunchKernelGGL((k_gemm2<3, true>), dim3(49 * 3), dim3(512), 0, stream,
                       Ot, Wp, (_Float16*)nullptr, out);
}